// Round 2
// baseline (8549.081 us; speedup 1.0000x reference)
//
#include <hip/hip_runtime.h>
#include <math.h>

#define NB 8
#define NC 64
#define NH 256
#define NW 256
#define NM 40      // 2*MODES1 (rows 0..19 and 236..255)
#define NKX 20     // MODES2
#define NL 4

// ---- per-chunk workspace pieces (in floats), cb = images per chunk ----
// H, H2      : cb*64*256*256        activation ping-pong
// FX (=Gy)   : cb*64*256*20 float2  x-DFT result / inverse-y result
// FXY, G     : cb*64*800 float2     fully-reduced modes / mixed modes
// WT         : 800*4096 float2      one layer's transposed spectral weights
// TX, TY     : twiddles; WC, BC    : combined conv weights/bias
#define PERCB_FLOATS ((size_t)(2*4194304 + 655360 + 2*102400))   // 9,248,768
#define FIXED_FLOATS ((size_t)(6553600 + 10240 + 20480 + 147456 + 256)) // 6,732,032

static __device__ __forceinline__ float gelu_f(float v) {
  return 0.5f * v * (1.f + erff(v * 0.70710678118654752f));
}

// ---------------------------------------------------------------------------
// Twiddle tables. Tx[kx][x] = (cos,sin)(2*pi*kx*x/256) for kx 0..19.
// Ty[m][y]  = (cos,sin)(2*pi*ky*y/256), ky = m (m<20) or m+216 (m>=20).
__global__ __launch_bounds__(256) void k_tables(float2* __restrict__ Tx,
                                                float2* __restrict__ Ty) {
  int t = blockIdx.x * 256 + threadIdx.x;
  const float w = (float)(2.0 * 3.14159265358979323846 / 256.0);
  if (t < NKX * 256) {
    int kx = t >> 8, x = t & 255;
    float th = (float)((kx * x) & 255) * w;
    Tx[t] = make_float2(cosf(th), sinf(th));
  }
  int u = t - NKX * 256;
  if (u >= 0 && u < NM * 256) {
    int m = u >> 8, y = u & 255;
    int ky = (m < 20) ? m : (m + 216);
    float th = (float)((ky * y) & 255) * w;
    Ty[u] = make_float2(cosf(th), sinf(th));
  }
}

// ---------------------------------------------------------------------------
// Combined conv weights: wc[(l, i, o, tap)] = convh + convw (+pw at center)
__global__ __launch_bounds__(256) void k_wc(const float* __restrict__ ch,
                                            const float* __restrict__ cw,
                                            const float* __restrict__ pw,
                                            const float* __restrict__ chb,
                                            const float* __restrict__ cwb,
                                            const float* __restrict__ pwb,
                                            float* __restrict__ wc,
                                            float* __restrict__ bc) {
  int t = blockIdx.x * 256 + threadIdx.x;
  if (t < NL * NC * NC * 9) {
    int tap = t % 9;
    int io  = t / 9;
    int o   = io % 64;
    int i   = (io / 64) % 64;
    int l   = io / 4096;
    int src = ((l * 64 + o) * 64 + i) * 9 + tap;
    float v = ch[src] + cw[src];
    if (tap == 4) v += pw[(l * 64 + o) * 64 + i];
    wc[t] = v;
  }
  if (t < NL * NC) bc[t] = chb[t] + cwb[t] + pwb[t];
}

// ---------------------------------------------------------------------------
// fc0 lift for chunk [b0, b0+cb): x (B,H,W,3) -> h (cb,C,H,W)
__global__ __launch_bounds__(256) void k_fc0(const float* __restrict__ x,
                                             const float* __restrict__ w,
                                             const float* __restrict__ b,
                                             float* __restrict__ h, int b0) {
  int t = blockIdx.x * 256 + threadIdx.x;    // cb*64*65536
  int xw = t & 255;
  int y  = (t >> 8) & 255;
  int c  = (t >> 16) & 63;
  int bb = t >> 22;                          // chunk-local image
  const float* xp = x + (((size_t)(b0 + bb) * 256 + y) * 256 + xw) * 3;
  h[t] = xp[0] * w[c] + xp[1] * w[64 + c] + xp[2] * w[128 + c] + b[c];
}

// ---------------------------------------------------------------------------
// Partial DFT along x: h rows (nrows of them, 256 wide) -> Fx[row][kx]
__global__ __launch_bounds__(256) void k_fwdx(const float* __restrict__ h,
                                              const float2* __restrict__ Tx,
                                              float2* __restrict__ Fx, int nrows) {
  __shared__ float sm[24 * 257];
  int row0 = blockIdx.x * 24;
  for (int t = threadIdx.x; t < 24 * 256; t += 256) {
    int r = t >> 8, xx = t & 255;
    int row = row0 + r;
    sm[r * 257 + xx] = (row < nrows) ? h[(size_t)row * 256 + xx] : 0.f;
  }
  __syncthreads();
  int t = threadIdx.x;
  if (t < 240) {
    int pair = t / 20, kx = t % 20;
    int r = pair * 2;
    const float* s0 = sm + r * 257;
    const float* s1 = sm + (r + 1) * 257;
    const float2* tw = Tx + kx * 256;
    float re0 = 0.f, im0 = 0.f, re1 = 0.f, im1 = 0.f;
    #pragma unroll 8
    for (int xx = 0; xx < 256; ++xx) {
      float2 w = tw[xx];
      float v0 = s0[xx], v1 = s1[xx];
      re0 += v0 * w.x; im0 -= v0 * w.y;
      re1 += v1 * w.x; im1 -= v1 * w.y;
    }
    int g0 = row0 + r, g1 = row0 + r + 1;
    if (g0 < nrows) Fx[(size_t)g0 * 20 + kx] = make_float2(re0, im0);
    if (g1 < nrows) Fx[(size_t)g1 * 20 + kx] = make_float2(re1, im1);
  }
}

// ---------------------------------------------------------------------------
// Partial DFT along y: Fx (bc,y,kx) -> Fxy (bc,m,kx), applies ortho scale 1/256.
__global__ __launch_bounds__(256) void k_fwdy(const float2* __restrict__ Fx,
                                              const float2* __restrict__ Ty,
                                              float2* __restrict__ Fxy) {
  int t  = blockIdx.x * 256 + threadIdx.x;   // cb*64*40*20
  int kx = t % 20;
  int m  = (t / 20) % 40;
  int bc = t / 800;
  const float2* fp = Fx + (size_t)bc * NH * 20 + kx;
  const float2* tp = Ty + m * 256;
  float re = 0.f, im = 0.f;
  #pragma unroll 4
  for (int y = 0; y < 256; ++y) {
    float2 f = fp[y * 20];
    float2 w = tp[y];                  // forward: multiply by conj -> e^{-i th}
    re += f.x * w.x + f.y * w.y;
    im += f.y * w.x - f.x * w.y;
  }
  Fxy[t] = make_float2(re * (1.f / 256.f), im * (1.f / 256.f));
}

// ---------------------------------------------------------------------------
// Transpose spectral weights of layer l: (i,o,m,kx) -> wT[(m*20+kx)*4096 + i*64+o]
// 256 threads: 32x8, 4 rows per thread.
__global__ __launch_bounds__(256) void k_wT(const float* __restrict__ w1,
                                            const float* __restrict__ w2,
                                            float2* __restrict__ wT, int l) {
  __shared__ float2 tile[32][33];
  int mk0 = blockIdx.x * 32;   // 25 blocks
  int io0 = blockIdx.y * 32;   // 128 blocks
  int tx = threadIdx.x & 31, ty0 = threadIdx.x >> 5;
  #pragma unroll
  for (int s = 0; s < 4; ++s) {
    int ty = ty0 * 4 + s;
    int mk = mk0 + tx, io = io0 + ty;
    int m = mk / 20, kx = mk % 20;
    const float* src = (m < 20) ? w1 : w2;
    int mm = (m < 20) ? m : (m - 20);
    size_t idx = ((((size_t)l * 4096 + io) * 20 + mm) * 20 + kx) * 2;
    tile[ty][tx] = make_float2(src[idx], src[idx + 1]);
  }
  __syncthreads();
  #pragma unroll
  for (int s = 0; s < 4; ++s) {
    int ty = ty0 * 4 + s;
    wT[(size_t)(mk0 + ty) * 4096 + (io0 + tx)] = tile[tx][ty];
  }
}

// ---------------------------------------------------------------------------
// Channel mix per mode: G[bc_out, mk] = sum_i Fxy[bc_in, mk] * W[i,o,mk]
__global__ __launch_bounds__(256) void k_mix(const float2* __restrict__ Fxy,
                                             const float2* __restrict__ wT,
                                             float2* __restrict__ G, int nrows) {
  __shared__ float2 sf[512];               // nrows = cb*64 <= 512
  int mk = blockIdx.x;
  for (int t = threadIdx.x; t < nrows; t += 256) sf[t] = Fxy[(size_t)t * 800 + mk];
  __syncthreads();
  const float2* wp = wT + (size_t)mk * 4096;
  for (int t = threadIdx.x; t < nrows; t += 256) {
    int b = t >> 6, o = t & 63;
    const float2* fb = sf + b * 64;
    float re = 0.f, im = 0.f;
    #pragma unroll 8
    for (int i = 0; i < 64; ++i) {
      float2 f = fb[i];
      float2 w = wp[i * 64 + o];
      re += f.x * w.x - f.y * w.y;
      im += f.x * w.y + f.y * w.x;
    }
    G[(size_t)(b * 64 + o) * 800 + mk] = make_float2(re, im);
  }
}

// ---------------------------------------------------------------------------
// Inverse DFT along y: G (bc,m,kx) -> Gy (bc,y,kx)
__global__ __launch_bounds__(256) void k_invy(const float2* __restrict__ G,
                                              const float2* __restrict__ Ty,
                                              float2* __restrict__ Gy) {
  int t  = blockIdx.x * 256 + threadIdx.x;   // cb*64*256*20
  int kx = t % 20;
  int y  = (t / 20) & 255;
  int bc = t / 5120;
  const float2* gp = G + (size_t)bc * 800 + kx;
  float re = 0.f, im = 0.f;
  #pragma unroll 4
  for (int m = 0; m < 40; ++m) {
    float2 g = gp[m * 20];
    float2 w = Ty[m * 256 + y];        // inverse: e^{+i th}
    re += g.x * w.x - g.y * w.y;
    im += g.x * w.y + g.y * w.x;
  }
  Gy[t] = make_float2(re, im);
}

// ---------------------------------------------------------------------------
// Fused: 3x3 conv (combined weights, bias) + inverse-x DFT (spectral add) + gelu
// Block = 256 threads = 8x32 output tile, one pixel/thread, acc over all 64 o.
__global__ __launch_bounds__(256) void k_conv(const float* __restrict__ hin,
                                              const float* __restrict__ wc,   // layer base
                                              const float* __restrict__ bcb,  // layer base
                                              const float2* __restrict__ Gy,
                                              const float2* __restrict__ Tx,
                                              float* __restrict__ hout,
                                              int dogelu) {
  __shared__ float sm[16 * 340];          // 16 in-ch x 10 rows x 34 cols
  __shared__ float2 smTx[19 * 32];        // kx=1..19 twiddles for this x-tile
  int bidx = blockIdx.x;
  int x0 = (bidx & 7) << 5;
  int y0 = ((bidx >> 3) & 31) << 3;
  int bb = bidx >> 8;                     // chunk-local image
  int px = threadIdx.x & 31, py = threadIdx.x >> 5;
  int y = y0 + py, x = x0 + px;

  for (int t = threadIdx.x; t < 19 * 32; t += 256)
    smTx[t] = Tx[(1 + (t >> 5)) * 256 + x0 + (t & 31)];

  float acc[64];
  #pragma unroll
  for (int o = 0; o < 64; ++o) acc[o] = bcb[o];

  for (int ci = 0; ci < 64; ci += 16) {
    __syncthreads();
    for (int t = threadIdx.x; t < 16 * 340; t += 256) {
      int i = t / 340, rem = t % 340;
      int r = rem / 34, cc = rem % 34;
      int gy = y0 - 1 + r, gx = x0 - 1 + cc;
      float v = 0.f;
      if (gy >= 0 && gy < NH && gx >= 0 && gx < NW)
        v = hin[(((size_t)bb * NC + ci + i) * NH + gy) * NW + gx];
      sm[t] = v;
    }
    __syncthreads();
    for (int i = 0; i < 16; ++i) {
      int base = i * 340 + py * 34 + px;
      float v00 = sm[base + 0],  v01 = sm[base + 1],  v02 = sm[base + 2];
      float v10 = sm[base + 34], v11 = sm[base + 35], v12 = sm[base + 36];
      float v20 = sm[base + 68], v21 = sm[base + 69], v22 = sm[base + 70];
      const float* wp = wc + (ci + i) * 576;   // uniform -> scalar loads
      #pragma unroll
      for (int o = 0; o < 64; ++o) {
        const float* wo = wp + o * 9;
        acc[o] += wo[0] * v00 + wo[1] * v01 + wo[2] * v02
                + wo[3] * v10 + wo[4] * v11 + wo[5] * v12
                + wo[6] * v20 + wo[7] * v21 + wo[8] * v22;
      }
    }
  }

  const float scale = 1.f / 256.f;
  #pragma unroll
  for (int o = 0; o < 64; ++o) {
    const float4* gp = (const float4*)(Gy + ((size_t)(bb * NC + o) * NH + y) * NKX);
    float4 g0 = gp[0];                       // kx0 (re,im), kx1 (re,im)
    float2 t1 = smTx[px];
    float s = g0.x + 2.f * (g0.z * t1.x - g0.w * t1.y);
    #pragma unroll
    for (int p = 1; p < 10; ++p) {
      float4 g  = gp[p];                     // kx=2p, kx=2p+1
      float2 ta = smTx[(2 * p - 1) * 32 + px];
      float2 tb = smTx[(2 * p) * 32 + px];
      s += 2.f * (g.x * ta.x - g.y * ta.y) + 2.f * (g.z * tb.x - g.w * tb.y);
    }
    float v = acc[o] + s * scale;
    if (dogelu) v = gelu_f(v);
    hout[((size_t)(bb * NC + o) * NH + y) * NW + x] = v;
  }
}

// ---------------------------------------------------------------------------
// Head: per pixel, fc1 (64->128) + exact gelu + fc2 (128->1)
__global__ __launch_bounds__(256) void k_head(const float* __restrict__ h,
                                              const float* __restrict__ w1,
                                              const float* __restrict__ b1,
                                              const float* __restrict__ w2,
                                              const float* __restrict__ b2,
                                              float* __restrict__ out, int b0) {
  int t  = blockIdx.x * 256 + threadIdx.x;  // cb*H*W
  int xw = t & 255;
  int y  = (t >> 8) & 255;
  int bb = t >> 16;                         // chunk-local
  float hv[64];
  const float* hp = h + (size_t)bb * NC * NH * NW + y * 256 + xw;
  #pragma unroll
  for (int c = 0; c < 64; ++c) hv[c] = hp[(size_t)c * NH * NW];
  float o = b2[0];
  for (int j = 0; j < 128; ++j) {
    float s = b1[j];
    #pragma unroll
    for (int c = 0; c < 64; ++c) s += hv[c] * w1[c * 128 + j];  // uniform -> s_load
    s = gelu_f(s);
    o += s * w2[j];
  }
  out[(size_t)(b0 << 16) + t] = o;
}

// ---------------------------------------------------------------------------
extern "C" void kernel_launch(void* const* d_in, const int* in_sizes, int n_in,
                              void* d_out, int out_size, void* d_ws, size_t ws_size,
                              hipStream_t stream) {
  const float* x    = (const float*)d_in[0];
  const float* fc0w = (const float*)d_in[1];
  const float* fc0b = (const float*)d_in[2];
  const float* w1   = (const float*)d_in[3];
  const float* w2   = (const float*)d_in[4];
  const float* chw  = (const float*)d_in[5];
  const float* chb  = (const float*)d_in[6];
  const float* cww  = (const float*)d_in[7];
  const float* cwb  = (const float*)d_in[8];
  const float* pww  = (const float*)d_in[9];
  const float* pwb  = (const float*)d_in[10];
  const float* fc1w = (const float*)d_in[11];
  const float* fc1b = (const float*)d_in[12];
  const float* fc2w = (const float*)d_in[13];
  const float* fc2b = (const float*)d_in[14];

  // Pick images-per-chunk from available workspace (deterministic per session).
  int cb = 1;
  for (int cand = 8; cand >= 1; cand >>= 1) {
    size_t need = (PERCB_FLOATS * (size_t)cand + FIXED_FLOATS) * sizeof(float);
    if (ws_size >= need) { cb = cand; break; }
  }

  const size_t szH  = (size_t)cb * 4194304;   // floats
  const size_t szFX = (size_t)cb * 655360;
  const size_t szG  = (size_t)cb * 102400;

  float*  ws  = (float*)d_ws;
  float*  h   = ws;
  float*  h2  = h + szH;
  float2* Fx  = (float2*)(h2 + szH);
  float2* Fxy = (float2*)((float*)Fx + szFX);
  float2* G   = (float2*)((float*)Fxy + szG);
  float2* wT  = (float2*)((float*)G + szG);
  float2* Tx  = (float2*)((float*)wT + 6553600);
  float2* Ty  = (float2*)((float*)Tx + 10240);
  float*  wcb = (float*)Ty + 20480;
  float*  bcb = wcb + 147456;
  float2* Gy  = Fx;   // Fx is dead after k_fwdy; reuse as Gy

  k_tables<<<60, 256, 0, stream>>>(Tx, Ty);
  k_wc<<<(NL * NC * NC * 9 + 255) / 256, 256, 0, stream>>>(chw, cww, pww, chb, cwb, pwb, wcb, bcb);

  for (int b0 = 0; b0 < NB; b0 += cb) {
    k_fc0<<<cb * 16384, 256, 0, stream>>>(x, fc0w, fc0b, h, b0);
    float* cur = h;
    float* nxt = h2;
    int nrows = cb * NC * NH;
    for (int l = 0; l < NL; ++l) {
      k_fwdx<<<(nrows + 23) / 24, 256, 0, stream>>>(cur, Tx, Fx, nrows);
      k_fwdy<<<cb * 200, 256, 0, stream>>>(Fx, Ty, Fxy);
      k_wT<<<dim3(25, 128), 256, 0, stream>>>(w1, w2, wT, l);
      k_mix<<<NM * NKX, 256, 0, stream>>>(Fxy, wT, G, cb * 64);
      k_invy<<<cb * 1280, 256, 0, stream>>>(G, Ty, Gy);
      k_conv<<<cb * 256, 256, 0, stream>>>(cur, wcb + (size_t)l * 36864,
                                           bcb + (size_t)l * 64, Gy, Tx, nxt,
                                           (l < NL - 1) ? 1 : 0);
      float* tmp = cur; cur = nxt; nxt = tmp;
    }
    k_head<<<cb * 256, 256, 0, stream>>>(cur, fc1w, fc1b, fc2w, fc2b,
                                         (float*)d_out, b0);
  }
}